// Round 2
// baseline (642.633 us; speedup 1.0000x reference)
//
#include <hip/hip_runtime.h>

#define NVOX 200000
#define KOFF 9
#define COUTC 64
#define TILE_N 64
#define BN_EPS 1e-5f

__device__ __forceinline__ float lrelu(float x) { return x > 0.0f ? x : 0.01f * x; }
__device__ __forceinline__ float bf2f(unsigned short h) {
    return __uint_as_float(((unsigned)h) << 16);
}
__device__ __forceinline__ unsigned short f2bf(float x) {   // round-nearest-even
    unsigned u = __float_as_uint(x);
    u += 0x7fffu + ((u >> 16) & 1u);
    return (unsigned short)(u >> 16);
}

// One kernel computes one sparse conv for two independent branches (blockIdx.y).
// Gather tile + weights staged in LDS; 4x4 outputs per thread; fused LeakyReLU
// and BN statistics (per-block reduction -> 64 atomics).
// IN_BF16: input features stored as bf16 (stage B); else f32 (stage A).
// Output goes to outH (bf16) if non-null for that branch, else outF (f32).
template<int CIN, bool AFF, bool IN_BF16>
__global__ __launch_bounds__(256) void conv_kernel(
    const void* __restrict__ X0, const void* __restrict__ X1,
    const int* __restrict__ nbr0, const int* __restrict__ nbr1,
    const int* __restrict__ msk0, const int* __restrict__ msk1,
    const float* __restrict__ Wp0, const float* __restrict__ Wp1,
    const float* __restrict__ aff0, const float* __restrict__ aff1,
    unsigned short* __restrict__ outH0, unsigned short* __restrict__ outH1,
    float* __restrict__ outF0, float* __restrict__ outF1,
    float* __restrict__ st0, float* __restrict__ st1)
{
    const int br = blockIdx.y;
    const void* Xv = br ? X1 : X0;
    const int* nbr = br ? nbr1 : nbr0;
    const int* msk = br ? msk1 : msk0;
    const float* Wp = br ? Wp1 : Wp0;
    const float* aff = br ? aff1 : aff0;
    unsigned short* outH = br ? outH1 : outH0;
    float* outF = br ? outF1 : outF0;
    float* st = br ? st1 : st0;

    constexpr int GSTR = CIN + 4;                    // 272B/136B row pitch, 16B aligned
    constexpr int LDSF = TILE_N * GSTR + CIN * COUTC;
    __shared__ float lds[LDSF];
    float* Gk = lds;
    float* Wk = lds + TILE_N * GSTR;

    const int tid = threadIdx.x;
    const int n0 = blockIdx.x * TILE_N;
    const int nb = tid >> 4;      // 0..15 -> 4 voxels each
    const int db = tid & 15;      // 0..15 -> 4 output channels each

    float acc[4][4] = {};

    for (int k = 0; k < KOFF; ++k) {
        __syncthreads();
        // ---- gather stage: G[row][c] = mask ? affine(X[nbr[k][n0+row]][c]) : 0
        if constexpr (!IN_BF16) {
            const float* X = (const float*)Xv;
            constexpr int LPR = CIN / 4;        // float4 chunks per row
            constexpr int ROWS = 256 / LPR;
            constexpr int PASS = TILE_N / ROWS;
            const int lane = tid & (LPR - 1);
            const int rbase = tid / LPR;
            #pragma unroll
            for (int p = 0; p < PASS; ++p) {
                const int row = rbase + p * ROWS;
                const int g = n0 + row;
                float4 v = make_float4(0.f, 0.f, 0.f, 0.f);
                if (msk[k * NVOX + g] != 0) {
                    const int src = nbr[k * NVOX + g];
                    v = *reinterpret_cast<const float4*>(X + (size_t)src * CIN + lane * 4);
                    if constexpr (AFF) {
                        float4 a = *reinterpret_cast<const float4*>(aff + lane * 4);
                        float4 b = *reinterpret_cast<const float4*>(aff + 64 + lane * 4);
                        v.x = fmaf(a.x, v.x, b.x);
                        v.y = fmaf(a.y, v.y, b.y);
                        v.z = fmaf(a.z, v.z, b.z);
                        v.w = fmaf(a.w, v.w, b.w);
                    }
                }
                *reinterpret_cast<float4*>(Gk + row * GSTR + lane * 4) = v;
            }
        } else {
            const unsigned short* X = (const unsigned short*)Xv;
            constexpr int LPR = CIN / 8;        // 16B (8 bf16) chunks per row
            constexpr int ROWS = 256 / LPR;
            constexpr int PASS = TILE_N / ROWS;
            const int lane = tid & (LPR - 1);
            const int rbase = tid / LPR;
            #pragma unroll
            for (int p = 0; p < PASS; ++p) {
                const int row = rbase + p * ROWS;
                const int g = n0 + row;
                float v[8] = {0.f,0.f,0.f,0.f,0.f,0.f,0.f,0.f};
                if (msk[k * NVOX + g] != 0) {
                    const int src = nbr[k * NVOX + g];
                    uint4 u = *reinterpret_cast<const uint4*>(X + (size_t)src * CIN + lane * 8);
                    unsigned uu[4] = {u.x, u.y, u.z, u.w};
                    #pragma unroll
                    for (int q = 0; q < 4; ++q) {
                        v[2*q]   = bf2f((unsigned short)(uu[q] & 0xffffu));
                        v[2*q+1] = bf2f((unsigned short)(uu[q] >> 16));
                    }
                    if constexpr (AFF) {
                        #pragma unroll
                        for (int j = 0; j < 8; ++j) {
                            const int c = lane * 8 + j;
                            v[j] = fmaf(aff[c], v[j], aff[64 + c]);
                        }
                    }
                }
                *reinterpret_cast<float4*>(Gk + row * GSTR + lane * 8) =
                    make_float4(v[0], v[1], v[2], v[3]);
                *reinterpret_cast<float4*>(Gk + row * GSTR + lane * 8 + 4) =
                    make_float4(v[4], v[5], v[6], v[7]);
            }
        }
        // ---- weight stage: Wk[c][d] for this k
        constexpr int WPASS = CIN * COUTC / 4 / 256;
        #pragma unroll
        for (int p = 0; p < WPASS; ++p) {
            const int idx = (tid + p * 256) * 4;
            *reinterpret_cast<float4*>(Wk + idx) =
                *reinterpret_cast<const float4*>(Wp + (size_t)k * CIN * COUTC + idx);
        }
        __syncthreads();
        // ---- compute: acc[i][j] += G[nb*4+i][c] * W[c][db*4+j]
        const float* gb = Gk + nb * 4 * GSTR;
        const float* wb = Wk + db * 4;
        #pragma unroll 8
        for (int c = 0; c < CIN; ++c) {
            float av[4];
            #pragma unroll
            for (int i = 0; i < 4; ++i) av[i] = gb[i * GSTR + c];
            float4 w = *reinterpret_cast<const float4*>(wb + c * COUTC);
            float wv[4] = {w.x, w.y, w.z, w.w};
            #pragma unroll
            for (int i = 0; i < 4; ++i)
                #pragma unroll
                for (int j = 0; j < 4; ++j)
                    acc[i][j] = fmaf(av[i], wv[j], acc[i][j]);
        }
    }

    // ---- epilogue: LeakyReLU + store + BN-stat partials
    float ps[4] = {0.f,0.f,0.f,0.f}, pss[4] = {0.f,0.f,0.f,0.f};
    #pragma unroll
    for (int i = 0; i < 4; ++i) {
        float v0 = lrelu(acc[i][0]);
        float v1 = lrelu(acc[i][1]);
        float v2 = lrelu(acc[i][2]);
        float v3 = lrelu(acc[i][3]);
        const size_t base = (size_t)(n0 + nb*4 + i) * COUTC + db*4;
        if (outH) {
            ushort4 h;
            h.x = f2bf(v0); h.y = f2bf(v1); h.z = f2bf(v2); h.w = f2bf(v3);
            *reinterpret_cast<ushort4*>(outH + base) = h;
        } else {
            *reinterpret_cast<float4*>(outF + base) = make_float4(v0, v1, v2, v3);
        }
        ps[0]+=v0; ps[1]+=v1; ps[2]+=v2; ps[3]+=v3;
        pss[0]+=v0*v0; pss[1]+=v1*v1; pss[2]+=v2*v2; pss[3]+=v3*v3;
    }
    __syncthreads();               // done reading Gk; reuse LDS for reduction
    float* red = lds;              // [2][16][64]
    *reinterpret_cast<float4*>(red + (0*16 + nb)*64 + db*4) = make_float4(ps[0],ps[1],ps[2],ps[3]);
    *reinterpret_cast<float4*>(red + (1*16 + nb)*64 + db*4) = make_float4(pss[0],pss[1],pss[2],pss[3]);
    __syncthreads();
    if (tid < 128) {
        const int arr = tid >> 6, d = tid & 63;
        float s = 0.f;
        #pragma unroll
        for (int q = 0; q < 16; ++q) s += red[(arr*16 + q)*64 + d];
        atomicAdd(st + arr*64 + d, s);
    }
}

__global__ void zero_kernel(float* __restrict__ p, int n) {
    int i = blockIdx.x * blockDim.x + threadIdx.x;
    if (i < n) p[i] = 0.f;
}

// stats -> affine: a = gamma * rsqrt(var+eps); b' = beta - mu*a
__global__ void finalize_kernel(const float* __restrict__ s0, const float* __restrict__ s1,
                                const float* __restrict__ g0, const float* __restrict__ b0,
                                const float* __restrict__ g1, const float* __restrict__ b1,
                                float* __restrict__ a0, float* __restrict__ a1)
{
    const int t = threadIdx.x;            // 128 threads
    const int br = t >> 6, d = t & 63;
    const float* st = br ? s1 : s0;
    const float* g  = br ? g1 : g0;
    const float* b  = br ? b1 : b0;
    float* aff      = br ? a1 : a0;
    const float inv_n = 1.0f / (float)NVOX;
    float mu  = st[d] * inv_n;
    float var = st[64 + d] * inv_n - mu * mu;
    float a = g[d] * rsqrtf(var + BN_EPS);
    aff[d]      = a;
    aff[64 + d] = b[d] - mu * a;
}

// out = aff2(ys) + aff3(yr), written in place over yr (= d_out, f32); ys is bf16
__global__ void combine_kernel(const unsigned short* __restrict__ ys, float* __restrict__ yr,
                               const float* __restrict__ aff2, const float* __restrict__ aff3)
{
    const int total = NVOX * COUTC / 4;
    for (int i = blockIdx.x * blockDim.x + threadIdx.x; i < total; i += gridDim.x * blockDim.x) {
        const int dq = (i & 15) * 4;
        ushort4 sh = reinterpret_cast<const ushort4*>(ys)[i];
        float4 r = reinterpret_cast<const float4*>(yr)[i];
        float4 a2 = *reinterpret_cast<const float4*>(aff2 + dq);
        float4 b2 = *reinterpret_cast<const float4*>(aff2 + 64 + dq);
        float4 a3 = *reinterpret_cast<const float4*>(aff3 + dq);
        float4 b3 = *reinterpret_cast<const float4*>(aff3 + 64 + dq);
        float4 o;
        o.x = fmaf(a2.x, bf2f(sh.x), b2.x) + fmaf(a3.x, r.x, b3.x);
        o.y = fmaf(a2.y, bf2f(sh.y), b2.y) + fmaf(a3.y, r.y, b3.y);
        o.z = fmaf(a2.z, bf2f(sh.z), b2.z) + fmaf(a3.z, r.z, b3.z);
        o.w = fmaf(a2.w, bf2f(sh.w), b2.w) + fmaf(a3.w, r.w, b3.w);
        reinterpret_cast<float4*>(yr)[i] = o;
    }
}

extern "C" void kernel_launch(void* const* d_in, const int* in_sizes, int n_in,
                              void* d_out, int out_size, void* d_ws, size_t ws_size,
                              hipStream_t stream) {
    const float* feats = (const float*)d_in[0];
    const float* W1    = (const float*)d_in[1];
    const float* W12   = (const float*)d_in[2];
    const float* W2    = (const float*)d_in[3];
    const float* W3    = (const float*)d_in[4];
    const float* g0  = (const float*)d_in[5];
    const float* b0  = (const float*)d_in[6];
    const float* g02 = (const float*)d_in[7];
    const float* b02 = (const float*)d_in[8];
    const float* g1  = (const float*)d_in[9];
    const float* b1  = (const float*)d_in[10];
    const float* g2  = (const float*)d_in[11];
    const float* b2  = (const float*)d_in[12];
    const int* nbrA  = (const int*)d_in[13];
    const int* maskA = (const int*)d_in[14];   // bool delivered as int32
    const int* nbrB  = (const int*)d_in[15];
    const int* maskB = (const int*)d_in[16];

    // ws layout (bf16 intermediates): y1, y2, ys then f32 stats+aff. ~76.9 MB total.
    const size_t buf = (size_t)NVOX * COUTC;
    unsigned short* y1 = (unsigned short*)d_ws;
    unsigned short* y2 = y1 + buf;
    unsigned short* ys = y2 + buf;
    float* stats = (float*)(ys + buf);   // 4 branches x {sum[64], sumsq[64]}
    float* aff   = stats + 512;          // 4 branches x {a[64], b'[64]}
    float* outf  = (float*)d_out;        // stage-B resA output lives in d_out (f32 scratch)

    dim3 gA(NVOX / TILE_N, 2);

    zero_kernel<<<2, 256, 0, stream>>>(stats, 512);

    // stage A: y1 = lrelu(conv(feats,nbrA,W1)); y2 = lrelu(conv(feats,nbrB,W2))
    conv_kernel<32, false, false><<<gA, 256, 0, stream>>>(
        feats, feats, nbrA, nbrB, maskA, maskB, W1, W2,
        nullptr, nullptr, y1, y2, nullptr, nullptr, stats, stats + 128);

    finalize_kernel<<<1, 128, 0, stream>>>(stats, stats + 128, g0, b0, g1, b1, aff, aff + 128);

    // stage B: ys = lrelu(conv(bn(y1),nbrB,W12)); outf = lrelu(conv(bn(y2),nbrA,W3))
    conv_kernel<64, true, true><<<gA, 256, 0, stream>>>(
        y1, y2, nbrB, nbrA, maskB, maskA, W12, W3,
        aff, aff + 128, ys, nullptr, nullptr, outf, stats + 256, stats + 384);

    finalize_kernel<<<1, 128, 0, stream>>>(stats + 256, stats + 384, g02, b02, g2, b2,
                                           aff + 256, aff + 384);

    combine_kernel<<<1024, 256, 0, stream>>>(ys, outf, aff + 256, aff + 384);
}

// Round 3
// 369.647 us; speedup vs baseline: 1.7385x; 1.7385x over previous
//
#include <hip/hip_runtime.h>

#define NVOX 200000
#define KOFF 9
#define BN_EPS 1e-5f

typedef unsigned short u16;
typedef __bf16 bf16x8 __attribute__((ext_vector_type(8)));
typedef float f32x4 __attribute__((ext_vector_type(4)));

__device__ __forceinline__ float lrelu(float x) { return x > 0.0f ? x : 0.01f * x; }
__device__ __forceinline__ float bf2f(u16 h) { return __uint_as_float(((unsigned)h) << 16); }
__device__ __forceinline__ u16 f2bf(float x) {   // round-nearest-even
    unsigned u = __float_as_uint(x);
    u += 0x7fffu + ((u >> 16) & 1u);
    return (u16)(u >> 16);
}

// MFMA sparse-conv: 64 voxels x 64 cout per block, 4 waves (wave w owns cols 16w..16w+15).
// Per k-offset: gather G[64][CIN] (bf16) + weights Wt[64 cout][CIN] into LDS, then
// mfma_f32_16x16x32_bf16 over 4 M-tiles x CIN/32 chunks. BIAS: mask-matrix MFMA adds
// the folded-BN bias term. Fused LeakyReLU + BN stats (shfl reduce -> 128 atomics).
template<int CIN, bool BIAS, bool IN_F32>
__global__ __launch_bounds__(256) void conv_mfma(
    const void* __restrict__ X0, const void* __restrict__ X1,
    const int* __restrict__ nbr0, const int* __restrict__ nbr1,
    const int* __restrict__ msk0, const int* __restrict__ msk1,
    const u16* __restrict__ Wt,           // [2][KOFF][64][CIN] bf16
    const u16* __restrict__ BWt,          // [2][64][32] bf16 (BIAS only)
    u16* __restrict__ outH0, u16* __restrict__ outH1,
    float* __restrict__ outF0, float* __restrict__ outF1,
    float* __restrict__ st0, float* __restrict__ st1)
{
    constexpr int GSTR = CIN + 8;          // bf16 row pitch; 16B aligned, even bank spread
    const int br = blockIdx.y;
    const void* Xv = br ? X1 : X0;
    const int* nbr = br ? nbr1 : nbr0;
    const int* msk = br ? msk1 : msk0;
    const u16* Wg = Wt + (size_t)br * KOFF * 64 * CIN;
    u16* outH = br ? outH1 : outH0;
    float* outF = br ? outF1 : outF0;
    float* st = br ? st1 : st0;

    __shared__ __align__(16) u16 sG[64 * GSTR];
    __shared__ __align__(16) u16 sW[64 * GSTR];
    __shared__ __align__(16) u16 sM[64 * 32];   // mask as bf16 0/1, k padded to 32
    __shared__ float red[128];

    const int tid = threadIdx.x;
    const int n0 = blockIdx.x * 64;
    const int wv = tid >> 6;
    const int l  = tid & 63;
    const int rl = l & 15;
    const int q  = l >> 4;
    const int colbase = wv * 16;

    const int gr = tid >> 2;        // gather: 4 threads per row
    const int gc = tid & 3;

    if constexpr (BIAS) {
        ((uint4*)sM)[tid] = make_uint4(0u, 0u, 0u, 0u);  // 256*16B = 4096B
    }

    f32x4 acc[4] = {};

    for (int k = 0; k < KOFF; ++k) {
        __syncthreads();
        // ---- gather stage
        const int g = n0 + gr;
        const int m = msk[k * NVOX + g];
        const int src = m ? nbr[k * NVOX + g] : 0;
        if constexpr (IN_F32) {
            const float* X = (const float*)Xv;
            float4 v0 = make_float4(0.f,0.f,0.f,0.f), v1 = v0;
            if (m) {
                const float* p = X + (size_t)src * CIN + gc * 8;
                v0 = *(const float4*)p;
                v1 = *(const float4*)(p + 4);
            }
            u16* d = sG + gr * GSTR + gc * 8;
            d[0]=f2bf(v0.x); d[1]=f2bf(v0.y); d[2]=f2bf(v0.z); d[3]=f2bf(v0.w);
            d[4]=f2bf(v1.x); d[5]=f2bf(v1.y); d[6]=f2bf(v1.z); d[7]=f2bf(v1.w);
        } else {
            const u16* X = (const u16*)Xv;
            uint4 u0 = make_uint4(0u,0u,0u,0u), u1 = u0;
            if (m) {
                const u16* p = X + (size_t)src * CIN + gc * 16;
                u0 = *(const uint4*)p;
                u1 = *(const uint4*)(p + 8);
            }
            *(uint4*)(sG + gr * GSTR + gc * 16) = u0;
            *(uint4*)(sG + gr * GSTR + gc * 16 + 8) = u1;
        }
        if constexpr (BIAS) {
            if (gc == 0) sM[gr * 32 + k] = m ? 0x3F80u : 0u;   // bf16 1.0 / 0.0
        }
        // ---- weight stage: Wt tile [64 cout][CIN] for this k
        constexpr int WP = (64 * CIN) / 8 / 256;   // uint4 copies per thread (1 or 2)
        #pragma unroll
        for (int p = 0; p < WP; ++p) {
            const int i8 = (tid + p * 256) * 8;
            const int d = i8 / CIN, c = i8 % CIN;
            *(uint4*)(sW + d * GSTR + c) =
                *(const uint4*)(Wg + (size_t)k * 64 * CIN + i8);
        }
        __syncthreads();
        // ---- MFMA compute
        bf16x8 bfr[CIN / 32];
        #pragma unroll
        for (int ch = 0; ch < CIN / 32; ++ch)
            bfr[ch] = *(const bf16x8*)(sW + (colbase + rl) * GSTR + ch * 32 + q * 8);
        #pragma unroll
        for (int mt = 0; mt < 4; ++mt) {
            #pragma unroll
            for (int ch = 0; ch < CIN / 32; ++ch) {
                bf16x8 afr = *(const bf16x8*)(sG + (mt * 16 + rl) * GSTR + ch * 32 + q * 8);
                acc[mt] = __builtin_amdgcn_mfma_f32_16x16x32_bf16(afr, bfr[ch], acc[mt], 0, 0, 0);
            }
        }
    }

    // ---- folded-BN bias via mask MFMA: acc += M(mask 0/1) x BW
    if constexpr (BIAS) {
        bf16x8 bw = *(const bf16x8*)(BWt + ((size_t)br * 64 + colbase + rl) * 32 + q * 8);
        #pragma unroll
        for (int mt = 0; mt < 4; ++mt) {
            bf16x8 mf = *(const bf16x8*)(sM + (mt * 16 + rl) * 32 + q * 8);
            acc[mt] = __builtin_amdgcn_mfma_f32_16x16x32_bf16(mf, bw, acc[mt], 0, 0, 0);
        }
    }

    // ---- epilogue: LeakyReLU + store + BN stats
    float ps = 0.f, pss = 0.f;
    #pragma unroll
    for (int mt = 0; mt < 4; ++mt) {
        #pragma unroll
        for (int i = 0; i < 4; ++i) {
            float v = lrelu(acc[mt][i]);
            const size_t o = (size_t)(n0 + mt * 16 + q * 4 + i) * 64 + colbase + rl;
            if (outH) outH[o] = f2bf(v);
            else      outF[o] = v;
            ps += v; pss += v * v;
        }
    }
    ps  += __shfl_xor(ps, 16);  ps  += __shfl_xor(ps, 32);
    pss += __shfl_xor(pss, 16); pss += __shfl_xor(pss, 32);
    if (l < 16) { red[colbase + rl] = ps; red[64 + colbase + rl] = pss; }
    __syncthreads();
    if (tid < 128) atomicAdd(st + (tid >> 6) * 64 + (tid & 63), red[tid]);
}

__global__ void zero_kernel(float* __restrict__ p, int n) {
    int i = blockIdx.x * blockDim.x + threadIdx.x;
    if (i < n) p[i] = 0.f;
}

// stage-A weights -> bf16, transposed: WtA[br][k][d][c] = bf16(W[k][c][d])
__global__ void wprepA(const float* __restrict__ W1, const float* __restrict__ W2,
                       u16* __restrict__ WtA)
{
    const int i = blockIdx.x * 256 + threadIdx.x;
    if (i >= 2 * KOFF * 64 * 32) return;
    const int br = i / (KOFF * 64 * 32);
    const int r  = i % (KOFF * 64 * 32);
    const int k  = r / (64 * 32);
    const int r2 = r % (64 * 32);
    const int d  = r2 / 32, c = r2 % 32;
    const float* W = br ? W2 : W1;
    WtA[i] = f2bf(W[((size_t)k * 32 + c) * 64 + d]);
}

// stage-B weights: fold input affine. WtB[br][k][d][c] = bf16(W[k][c][d]*a[c]);
// BWt[br][d][k(pad32)] = bf16(sum_c b'[c]*W[k][c][d])
__global__ void wprepB(const float* __restrict__ W12, const float* __restrict__ W3,
                       const float* __restrict__ affA, u16* __restrict__ WtB,
                       u16* __restrict__ BWt)
{
    const int i = blockIdx.x * 256 + threadIdx.x;
    if (i >= 2 * KOFF * 64) return;
    const int br = i / (KOFF * 64);
    const int r  = i % (KOFF * 64);
    const int k  = r / 64, d = r % 64;
    const float* W = br ? W3 : W12;
    const float* a = affA + br * 128;
    const float* b = a + 64;
    float bw = 0.f;
    u16* wrow = WtB + (((size_t)br * KOFF + k) * 64 + d) * 64;
    #pragma unroll 8
    for (int c = 0; c < 64; ++c) {
        const float wv = W[((size_t)k * 64 + c) * 64 + d];
        wrow[c] = f2bf(wv * a[c]);
        bw += wv * b[c];
    }
    u16* brow = BWt + ((size_t)br * 64 + d) * 32;
    brow[k] = f2bf(bw);
    if (k == 0) {
        for (int kk = KOFF; kk < 32; ++kk) brow[kk] = 0;
    }
}

// stats -> affine: a = gamma * rsqrt(var+eps); b' = beta - mu*a
__global__ void finalize_kernel(const float* __restrict__ s0, const float* __restrict__ s1,
                                const float* __restrict__ g0, const float* __restrict__ b0,
                                const float* __restrict__ g1, const float* __restrict__ b1,
                                float* __restrict__ a0, float* __restrict__ a1)
{
    const int t = threadIdx.x;            // 128 threads
    const int br = t >> 6, d = t & 63;
    const float* st = br ? s1 : s0;
    const float* g  = br ? g1 : g0;
    const float* b  = br ? b1 : b0;
    float* aff      = br ? a1 : a0;
    const float inv_n = 1.0f / (float)NVOX;
    float mu  = st[d] * inv_n;
    float var = st[64 + d] * inv_n - mu * mu;
    float a = g[d] * rsqrtf(var + BN_EPS);
    aff[d]      = a;
    aff[64 + d] = b[d] - mu * a;
}

// out = aff2(ys) + aff3(yr), in place over yr (= d_out, f32); ys is bf16
__global__ void combine_kernel(const u16* __restrict__ ys, float* __restrict__ yr,
                               const float* __restrict__ aff2, const float* __restrict__ aff3)
{
    const int total = NVOX * 64 / 4;
    for (int i = blockIdx.x * blockDim.x + threadIdx.x; i < total; i += gridDim.x * blockDim.x) {
        const int dq = (i & 15) * 4;
        ushort4 sh = reinterpret_cast<const ushort4*>(ys)[i];
        float4 r = reinterpret_cast<const float4*>(yr)[i];
        float4 a2 = *reinterpret_cast<const float4*>(aff2 + dq);
        float4 b2 = *reinterpret_cast<const float4*>(aff2 + 64 + dq);
        float4 a3 = *reinterpret_cast<const float4*>(aff3 + dq);
        float4 b3 = *reinterpret_cast<const float4*>(aff3 + 64 + dq);
        float4 o;
        o.x = fmaf(a2.x, bf2f(sh.x), b2.x) + fmaf(a3.x, r.x, b3.x);
        o.y = fmaf(a2.y, bf2f(sh.y), b2.y) + fmaf(a3.y, r.y, b3.y);
        o.z = fmaf(a2.z, bf2f(sh.z), b2.z) + fmaf(a3.z, r.z, b3.z);
        o.w = fmaf(a2.w, bf2f(sh.w), b2.w) + fmaf(a3.w, r.w, b3.w);
        reinterpret_cast<float4*>(yr)[i] = o;
    }
}

extern "C" void kernel_launch(void* const* d_in, const int* in_sizes, int n_in,
                              void* d_out, int out_size, void* d_ws, size_t ws_size,
                              hipStream_t stream) {
    const float* feats = (const float*)d_in[0];
    const float* W1    = (const float*)d_in[1];
    const float* W12   = (const float*)d_in[2];
    const float* W2    = (const float*)d_in[3];
    const float* W3    = (const float*)d_in[4];
    const float* g0  = (const float*)d_in[5];
    const float* b0  = (const float*)d_in[6];
    const float* g02 = (const float*)d_in[7];
    const float* b02 = (const float*)d_in[8];
    const float* g1  = (const float*)d_in[9];
    const float* b1  = (const float*)d_in[10];
    const float* g2  = (const float*)d_in[11];
    const float* b2  = (const float*)d_in[12];
    const int* nbrA  = (const int*)d_in[13];
    const int* maskA = (const int*)d_in[14];   // bool delivered as int32
    const int* nbrB  = (const int*)d_in[15];
    const int* maskB = (const int*)d_in[16];

    // ws layout: bf16 activations + bf16 weights, then f32 stats/aff (~77 MB)
    const size_t buf = (size_t)NVOX * 64;
    u16* y1  = (u16*)d_ws;
    u16* y2  = y1 + buf;
    u16* ys  = y2 + buf;
    u16* WtA = ys + buf;                 // 2*9*64*32 = 36864
    u16* WtB = WtA + 2 * KOFF * 64 * 32; // 2*9*64*64 = 73728
    u16* BWt = WtB + 2 * KOFF * 64 * 64; // 2*64*32   = 4096
    float* stats = (float*)(BWt + 2 * 64 * 32);  // 4 branches x {sum[64], sumsq[64]}
    float* aff   = stats + 512;                  // 4 branches x {a[64], b'[64]}
    float* outf  = (float*)d_out;        // stage-B resA output lives in d_out

    dim3 gA(NVOX / 64, 2);

    zero_kernel<<<2, 256, 0, stream>>>(stats, 512);
    wprepA<<<(2 * KOFF * 64 * 32) / 256, 256, 0, stream>>>(W1, W2, WtA);

    // stage A: y1 = lrelu(conv(feats,nbrA,W1)); y2 = lrelu(conv(feats,nbrB,W2))
    conv_mfma<32, false, true><<<gA, 256, 0, stream>>>(
        feats, feats, nbrA, nbrB, maskA, maskB, WtA, nullptr,
        y1, y2, nullptr, nullptr, stats, stats + 128);

    finalize_kernel<<<1, 128, 0, stream>>>(stats, stats + 128, g0, b0, g1, b1, aff, aff + 128);

    wprepB<<<(2 * KOFF * 64 + 255) / 256, 256, 0, stream>>>(W12, W3, aff, WtB, BWt);

    // stage B: ys = lrelu(conv(bn(y1),nbrB,W12)); outf = lrelu(conv(bn(y2),nbrA,W3))
    conv_mfma<64, true, false><<<gA, 256, 0, stream>>>(
        y1, y2, nbrB, nbrA, maskB, maskA, WtB, BWt,
        ys, nullptr, nullptr, outf, stats + 256, stats + 384);

    finalize_kernel<<<1, 128, 0, stream>>>(stats + 256, stats + 384, g02, b02, g2, b2,
                                           aff + 256, aff + 384);

    combine_kernel<<<1024, 256, 0, stream>>>(ys, outf, aff + 256, aff + 384);
}

// Round 4
// 335.524 us; speedup vs baseline: 1.9153x; 1.1017x over previous
//
#include <hip/hip_runtime.h>

#define NVOX 200000
#define KOFF 9
#define BN_EPS 1e-5f

typedef unsigned short u16;
typedef __bf16 bf16x8 __attribute__((ext_vector_type(8)));
typedef float f32x4 __attribute__((ext_vector_type(4)));

__device__ __forceinline__ float lrelu(float x) { return x > 0.0f ? x : 0.01f * x; }
__device__ __forceinline__ float bf2f(u16 h) { return __uint_as_float(((unsigned)h) << 16); }
__device__ __forceinline__ u16 f2bf(float x) {   // round-nearest-even
    unsigned u = __float_as_uint(x);
    u += 0x7fffu + ((u >> 16) & 1u);
    return (u16)(u >> 16);
}
__device__ __forceinline__ unsigned pkbf(float a, float b) {
    return (unsigned)f2bf(a) | ((unsigned)f2bf(b) << 16);
}

template<int CIN, bool IN_F32>
__device__ __forceinline__ void gather_issue(const void* __restrict__ Xv, int src, int gc,
        float4& f0, float4& f1, uint4& u0, uint4& u1)
{
    if constexpr (IN_F32) {
        f0 = make_float4(0.f, 0.f, 0.f, 0.f); f1 = f0;
        if (src >= 0) {
            const float* p = (const float*)Xv + (size_t)src * CIN + gc * 8;
            f0 = ((const float4*)p)[0];
            f1 = ((const float4*)p)[1];
        }
    } else {
        u0 = make_uint4(0u, 0u, 0u, 0u); u1 = u0;
        if (src >= 0) {
            const u16* p = (const u16*)Xv + (size_t)src * CIN + gc * 16;
            u0 = ((const uint4*)p)[0];
            u1 = ((const uint4*)p)[1];
        }
    }
}

template<int CIN, bool IN_F32, int GSTR>
__device__ __forceinline__ void gather_store(u16* __restrict__ sGb, int gr, int gc,
        const float4& f0, const float4& f1, const uint4& u0, const uint4& u1)
{
    if constexpr (IN_F32) {
        uint4 o = make_uint4(pkbf(f0.x, f0.y), pkbf(f0.z, f0.w),
                             pkbf(f1.x, f1.y), pkbf(f1.z, f1.w));
        *(uint4*)(sGb + gr * GSTR + gc * 8) = o;
    } else {
        *(uint4*)(sGb + gr * GSTR + gc * 16) = u0;
        *(uint4*)(sGb + gr * GSTR + gc * 16 + 8) = u1;
    }
}

// MFMA sparse-conv, latency-pipelined:
//  - all 9 mask/nbr indices preloaded to registers (independent loads, no chain)
//  - weight B-fragments held in registers for all 9 offsets (no weight LDS)
//  - gather double-buffered in LDS: one barrier per k; k+1 gather issued before
//    k's MFMA, written to the other buffer after (issue-early / write-late)
// 64 voxels x 64 cout per block, 4 waves; wave w owns cols 16w..16w+15.
template<int CIN, bool BIAS, bool IN_F32>
__global__ __launch_bounds__(256, 4) void conv_mfma(
    const void* __restrict__ X0, const void* __restrict__ X1,
    const int* __restrict__ nbr0, const int* __restrict__ nbr1,
    const int* __restrict__ msk0, const int* __restrict__ msk1,
    const u16* __restrict__ Wt,           // [2][KOFF][64][CIN] bf16
    const u16* __restrict__ BWt,          // [2][64][32] bf16 (BIAS only)
    u16* __restrict__ outH0, u16* __restrict__ outH1,
    float* __restrict__ outF0, float* __restrict__ outF1,
    float* __restrict__ st0, float* __restrict__ st1)
{
    constexpr int GSTR = CIN + 8;          // bf16 row pitch
    const int br = blockIdx.y;
    const void* Xv = br ? X1 : X0;
    const int* nbr = br ? nbr1 : nbr0;
    const int* msk = br ? msk1 : msk0;
    const u16* Wg = Wt + (size_t)br * KOFF * 64 * CIN;
    u16* outH = br ? outH1 : outH0;
    float* outF = br ? outF1 : outF0;
    float* st = br ? st1 : st0;

    __shared__ __align__(16) u16 sG[2][64 * GSTR];
    __shared__ __align__(16) u16 sM[64 * 32];   // mask as bf16 0/1, k padded to 32
    __shared__ float red[128];

    const int tid = threadIdx.x;
    const int n0 = blockIdx.x * 64;
    const int wv = tid >> 6;
    const int l  = tid & 63;
    const int rl = l & 15;
    const int q  = l >> 4;
    const int colbase = wv * 16;
    const int gr = tid >> 2;        // gather: 4 threads per row
    const int gc = tid & 3;

    // ---- preload all neighbor indices for this thread's gather row (mask folded to -1)
    int srcs[KOFF];
    {
        int mk[KOFF], nb[KOFF];
        #pragma unroll
        for (int k = 0; k < KOFF; ++k) {
            mk[k] = msk[k * NVOX + n0 + gr];
            nb[k] = nbr[k * NVOX + n0 + gr];
        }
        #pragma unroll
        for (int k = 0; k < KOFF; ++k) srcs[k] = mk[k] ? nb[k] : -1;
    }
    int mbits = 0;
    #pragma unroll
    for (int k = 0; k < KOFF; ++k) mbits |= (srcs[k] >= 0) ? (1 << k) : 0;

    // ---- mask matrix for the folded-BN bias MFMA (ordered before use by loop barriers)
    if constexpr (BIAS) {
        #pragma unroll
        for (int j = 0; j < 8; ++j) {
            const int k = gc * 8 + j;
            sM[gr * 32 + k] = ((k < KOFF) && ((mbits >> k) & 1)) ? (u16)0x3F80 : (u16)0;
        }
    }

    // ---- weight B-fragments for all offsets -> registers (L2-hot broadcast loads)
    bf16x8 wreg[KOFF][CIN / 32];
    #pragma unroll
    for (int k = 0; k < KOFF; ++k)
        #pragma unroll
        for (int ch = 0; ch < CIN / 32; ++ch)
            wreg[k][ch] = *(const bf16x8*)(Wg + ((size_t)k * 64 + colbase + rl) * CIN
                                           + ch * 32 + q * 8);

    // ---- software-pipelined gather + MFMA
    float4 pf0, pf1; uint4 pu0, pu1;
    gather_issue<CIN, IN_F32>(Xv, srcs[0], gc, pf0, pf1, pu0, pu1);
    gather_store<CIN, IN_F32, GSTR>(&sG[0][0], gr, gc, pf0, pf1, pu0, pu1);

    f32x4 acc[4] = {};
    #pragma unroll
    for (int k = 0; k < KOFF; ++k) {
        __syncthreads();                             // buffer k&1 ready; k-1 reads drained
        if (k + 1 < KOFF)
            gather_issue<CIN, IN_F32>(Xv, srcs[k + 1], gc, pf0, pf1, pu0, pu1);
        const u16* sgb = &sG[k & 1][0];
        #pragma unroll
        for (int mt = 0; mt < 4; ++mt)
            #pragma unroll
            for (int ch = 0; ch < CIN / 32; ++ch) {
                bf16x8 afr = *(const bf16x8*)(sgb + (mt * 16 + rl) * GSTR + ch * 32 + q * 8);
                acc[mt] = __builtin_amdgcn_mfma_f32_16x16x32_bf16(afr, wreg[k][ch], acc[mt], 0, 0, 0);
            }
        if (k + 1 < KOFF)
            gather_store<CIN, IN_F32, GSTR>(&sG[(k + 1) & 1][0], gr, gc, pf0, pf1, pu0, pu1);
    }

    // ---- folded-BN bias via mask MFMA: acc += M(mask 0/1) x BW
    if constexpr (BIAS) {
        bf16x8 bw = *(const bf16x8*)(BWt + ((size_t)br * 64 + colbase + rl) * 32 + q * 8);
        #pragma unroll
        for (int mt = 0; mt < 4; ++mt) {
            bf16x8 mf = *(const bf16x8*)(sM + (mt * 16 + rl) * 32 + q * 8);
            acc[mt] = __builtin_amdgcn_mfma_f32_16x16x32_bf16(mf, bw, acc[mt], 0, 0, 0);
        }
    }

    // ---- epilogue: LeakyReLU + store + BN stats
    float ps = 0.f, pss = 0.f;
    #pragma unroll
    for (int mt = 0; mt < 4; ++mt) {
        #pragma unroll
        for (int i = 0; i < 4; ++i) {
            float v = lrelu(acc[mt][i]);
            const size_t o = (size_t)(n0 + mt * 16 + q * 4 + i) * 64 + colbase + rl;
            if (outH) outH[o] = f2bf(v);
            else      outF[o] = v;
            ps += v; pss += v * v;
        }
    }
    ps  += __shfl_xor(ps, 16);  ps  += __shfl_xor(ps, 32);
    pss += __shfl_xor(pss, 16); pss += __shfl_xor(pss, 32);
    if (l < 16) { red[colbase + rl] = ps; red[64 + colbase + rl] = pss; }
    __syncthreads();
    if (tid < 128) atomicAdd(st + (tid >> 6) * 64 + (tid & 63), red[tid]);
}

// blocks 0..143: stage-A weights -> bf16 transposed WtA[br][k][d][c] = bf16(W[k][c][d]).
// block 144: zero the stats scratch (required every call — graph replays don't re-poison).
__global__ void prep0(const float* __restrict__ W1, const float* __restrict__ W2,
                      u16* __restrict__ WtA, float* __restrict__ stats)
{
    if (blockIdx.x == 144) {
        stats[threadIdx.x] = 0.f;
        stats[threadIdx.x + 256] = 0.f;
        return;
    }
    const int i = blockIdx.x * 256 + threadIdx.x;    // exactly 2*9*64*32 = 144*256
    const int br = i / (KOFF * 64 * 32);
    const int r  = i % (KOFF * 64 * 32);
    const int k  = r / (64 * 32);
    const int r2 = r % (64 * 32);
    const int d  = r2 / 32, c = r2 % 32;
    const float* W = br ? W2 : W1;
    WtA[i] = f2bf(W[((size_t)k * 32 + c) * 64 + d]);
}

// finalize stage-A BN (in LDS) + fold it into stage-B weights:
// WtB[br][k][d][c] = bf16(W[k][c][d]*a[c]); BWt[br][d][k(pad32)] = bf16(sum_c b'[c]*W[k][c][d])
__global__ void wprepB(const float* __restrict__ W12, const float* __restrict__ W3,
                       const float* __restrict__ stats,
                       const float* __restrict__ g0, const float* __restrict__ b0,
                       const float* __restrict__ g1, const float* __restrict__ b1,
                       u16* __restrict__ WtB, u16* __restrict__ BWt)
{
    __shared__ float sa[256];                 // [br][{a[64], b'[64]}]
    const int t = threadIdx.x;
    if (t < 128) {
        const int br = t >> 6, d = t & 63;
        const float* stp = stats + br * 128;
        const float* g = br ? g1 : g0;
        const float* b = br ? b1 : b0;
        const float inv_n = 1.0f / (float)NVOX;
        float mu  = stp[d] * inv_n;
        float var = stp[64 + d] * inv_n - mu * mu;
        float a = g[d] * rsqrtf(var + BN_EPS);
        sa[br * 128 + d] = a;
        sa[br * 128 + 64 + d] = b[d] - mu * a;
    }
    __syncthreads();
    const int i = blockIdx.x * 256 + t;
    if (i >= 2 * KOFF * 64) return;
    const int br = i / (KOFF * 64);
    const int r  = i % (KOFF * 64);
    const int k  = r / 64, d = r % 64;
    const float* W = br ? W3 : W12;
    const float* a = sa + br * 128;
    const float* bb = a + 64;
    float bw = 0.f;
    u16* wrow = WtB + (((size_t)br * KOFF + k) * 64 + d) * 64;
    #pragma unroll 8
    for (int c = 0; c < 64; ++c) {
        const float wv = W[((size_t)k * 64 + c) * 64 + d];
        wrow[c] = f2bf(wv * a[c]);
        bw += wv * bb[c];
    }
    u16* brow = BWt + ((size_t)br * 64 + d) * 32;
    brow[k] = f2bf(bw);
    if (k == 0) {
        for (int kk = KOFF; kk < 32; ++kk) brow[kk] = 0;
    }
}

// finalize stage-B BN (in LDS) + out = aff2(ys) + aff3(yr), in place over yr (= d_out)
__global__ void combine_kernel(const u16* __restrict__ ys, float* __restrict__ yr,
                               const float* __restrict__ stats,   // stage-B stats base
                               const float* __restrict__ g02, const float* __restrict__ b02,
                               const float* __restrict__ g2, const float* __restrict__ b2)
{
    __shared__ float sc[256];                 // [br][{a[64], b'[64]}]; br0=ys, br1=yr
    const int t = threadIdx.x;
    if (t < 128) {
        const int br = t >> 6, d = t & 63;
        const float* stp = stats + br * 128;
        const float* g = br ? g2 : g02;
        const float* b = br ? b2 : b02;
        const float inv_n = 1.0f / (float)NVOX;
        float mu  = stp[d] * inv_n;
        float var = stp[64 + d] * inv_n - mu * mu;
        float a = g[d] * rsqrtf(var + BN_EPS);
        sc[br * 128 + d] = a;
        sc[br * 128 + 64 + d] = b[d] - mu * a;
    }
    __syncthreads();
    const int total = NVOX * 64 / 4;
    for (int i = blockIdx.x * blockDim.x + t; i < total; i += gridDim.x * blockDim.x) {
        const int dq = (i & 15) * 4;
        ushort4 sh = reinterpret_cast<const ushort4*>(ys)[i];
        float4 r = reinterpret_cast<const float4*>(yr)[i];
        float4 a2 = *(const float4*)(sc + dq);
        float4 b2v = *(const float4*)(sc + 64 + dq);
        float4 a3 = *(const float4*)(sc + 128 + dq);
        float4 b3v = *(const float4*)(sc + 128 + 64 + dq);
        float4 o;
        o.x = fmaf(a2.x, bf2f(sh.x), b2v.x) + fmaf(a3.x, r.x, b3v.x);
        o.y = fmaf(a2.y, bf2f(sh.y), b2v.y) + fmaf(a3.y, r.y, b3v.y);
        o.z = fmaf(a2.z, bf2f(sh.z), b2v.z) + fmaf(a3.z, r.z, b3v.z);
        o.w = fmaf(a2.w, bf2f(sh.w), b2v.w) + fmaf(a3.w, r.w, b3v.w);
        reinterpret_cast<float4*>(yr)[i] = o;
    }
}

extern "C" void kernel_launch(void* const* d_in, const int* in_sizes, int n_in,
                              void* d_out, int out_size, void* d_ws, size_t ws_size,
                              hipStream_t stream) {
    const float* feats = (const float*)d_in[0];
    const float* W1    = (const float*)d_in[1];
    const float* W12   = (const float*)d_in[2];
    const float* W2    = (const float*)d_in[3];
    const float* W3    = (const float*)d_in[4];
    const float* g0  = (const float*)d_in[5];
    const float* b0  = (const float*)d_in[6];
    const float* g02 = (const float*)d_in[7];
    const float* b02 = (const float*)d_in[8];
    const float* g1  = (const float*)d_in[9];
    const float* b1  = (const float*)d_in[10];
    const float* g2  = (const float*)d_in[11];
    const float* b2  = (const float*)d_in[12];
    const int* nbrA  = (const int*)d_in[13];
    const int* maskA = (const int*)d_in[14];   // bool delivered as int32
    const int* nbrB  = (const int*)d_in[15];
    const int* maskB = (const int*)d_in[16];

    // ws layout: bf16 activations + bf16 weights, then f32 stats (~77 MB)
    const size_t buf = (size_t)NVOX * 64;
    u16* y1  = (u16*)d_ws;
    u16* y2  = y1 + buf;
    u16* ys  = y2 + buf;
    u16* WtA = ys + buf;                 // 2*9*64*32 = 36864
    u16* WtB = WtA + 2 * KOFF * 64 * 32; // 2*9*64*64 = 73728
    u16* BWt = WtB + 2 * KOFF * 64 * 64; // 2*64*32   = 4096
    float* stats = (float*)(BWt + 2 * 64 * 32);  // 4 branches x {sum[64], sumsq[64]}
    float* outf  = (float*)d_out;        // stage-B resA output lives in d_out

    dim3 gA(NVOX / 64, 2);

    prep0<<<145, 256, 0, stream>>>(W1, W2, WtA, stats);

    // stage A: y1 = lrelu(conv(feats,nbrA,W1)); y2 = lrelu(conv(feats,nbrB,W2))
    conv_mfma<32, false, true><<<gA, 256, 0, stream>>>(
        feats, feats, nbrA, nbrB, maskA, maskB, WtA, nullptr,
        y1, y2, nullptr, nullptr, stats, stats + 128);

    wprepB<<<5, 256, 0, stream>>>(W12, W3, stats, g0, b0, g1, b1, WtB, BWt);

    // stage B: ys = lrelu(conv(bn(y1),nbrB,W12)); outf = lrelu(conv(bn(y2),nbrA,W3))
    conv_mfma<64, true, false><<<gA, 256, 0, stream>>>(
        y1, y2, nbrB, nbrA, maskB, maskA, WtB, BWt,
        ys, nullptr, nullptr, outf, stats + 256, stats + 384);

    combine_kernel<<<1024, 256, 0, stream>>>(ys, outf, stats + 256, g02, b02, g2, b2);
}

// Round 5
// 183.379 us; speedup vs baseline: 3.5044x; 1.8297x over previous
//
#include <hip/hip_runtime.h>

#define NVOX 200000
#define KOFF 9
#define NSHARD 32
#define BN_EPS 1e-5f

typedef unsigned short u16;
typedef __bf16 bf16x8 __attribute__((ext_vector_type(8)));
typedef float f32x4 __attribute__((ext_vector_type(4)));

__device__ __forceinline__ float lrelu(float x) { return x > 0.0f ? x : 0.01f * x; }
__device__ __forceinline__ float bf2f(u16 h) { return __uint_as_float(((unsigned)h) << 16); }
__device__ __forceinline__ u16 f2bf(float x) {   // round-nearest-even
    unsigned u = __float_as_uint(x);
    u += 0x7fffu + ((u >> 16) & 1u);
    return (u16)(u >> 16);
}
__device__ __forceinline__ unsigned pkbf(float a, float b) {
    return (unsigned)f2bf(a) | ((unsigned)f2bf(b) << 16);
}

// MFMA sparse-conv, deep-pipelined, bf16-in:
//  - all 9 mask/nbr indices preloaded (independent loads)
//  - gather ring: 3 LDS slots, loads for offset k issued at iteration k-2
//    (2 reg sets in flight), ONE barrier per iteration
//  - BN stats: 32-way sharded atomics (kills same-line RMW contention)
// 64 voxels x 64 cout per block, 4 waves; wave w owns cols 16w..16w+15.
template<int CIN, bool BIAS>
__global__ __launch_bounds__(256, 4) void conv_mfma(
    const u16* __restrict__ X0, const u16* __restrict__ X1,
    const int* __restrict__ nbr0, const int* __restrict__ nbr1,
    const int* __restrict__ msk0, const int* __restrict__ msk1,
    const u16* __restrict__ Wt,           // [2][KOFF][64][CIN] bf16
    const u16* __restrict__ BWt,          // [2][64][32] bf16 (BIAS only)
    u16* __restrict__ outH0, u16* __restrict__ outH1,
    float* __restrict__ outF0, float* __restrict__ outF1,
    float* __restrict__ st0, float* __restrict__ st1)
{
    constexpr int GSTR = CIN + 8;          // bf16 row pitch (16B-aligned)
    constexpr int NLD = CIN / 32;          // uint4 gather loads per thread (1 or 2)
    const int br = blockIdx.y;
    const u16* X = br ? X1 : X0;
    const int* nbr = br ? nbr1 : nbr0;
    const int* msk = br ? msk1 : msk0;
    const u16* Wg = Wt + (size_t)br * KOFF * 64 * CIN;
    u16* outH = br ? outH1 : outH0;
    float* outF = br ? outF1 : outF0;
    float* st = br ? st1 : st0;

    __shared__ __align__(16) u16 sG[3][64 * GSTR];
    __shared__ __align__(16) u16 sM[BIAS ? 64 * 32 : 8];

    const int tid = threadIdx.x;
    const int n0 = blockIdx.x * 64;
    const int wv = tid >> 6;
    const int l  = tid & 63;
    const int rl = l & 15;
    const int q  = l >> 4;
    const int colbase = wv * 16;
    const int gr = tid >> 2;        // gather: 4 threads per row
    const int gc = tid & 3;

    // ---- preload all neighbor indices (mask folded to -1)
    int srcs[KOFF];
    #pragma unroll
    for (int k = 0; k < KOFF; ++k) {
        const int m  = msk[k * NVOX + n0 + gr];
        const int nb = nbr[k * NVOX + n0 + gr];
        srcs[k] = m ? nb : -1;
    }

    // ---- mask matrix for folded-BN bias MFMA (visible after loop barriers)
    if constexpr (BIAS) {
        #pragma unroll
        for (int j = 0; j < 8; ++j) {
            const int k = gc * 8 + j;
            sM[gr * 32 + k] = ((k < KOFF) && (srcs[k] >= 0)) ? (u16)0x3F80 : (u16)0;
        }
    }

    // ---- weight B-fragments (L2-hot; compiler may rematerialize under VGPR cap)
    bf16x8 wreg[KOFF][NLD];
    #pragma unroll
    for (int k = 0; k < KOFF; ++k)
        #pragma unroll
        for (int ch = 0; ch < NLD; ++ch)
            wreg[k][ch] = *(const bf16x8*)(Wg + ((size_t)k * 64 + colbase + rl) * CIN
                                           + ch * 32 + q * 8);

    uint4 g[2][NLD];
    auto issue = [&](int k, int s) {
        const int src = srcs[k];
        #pragma unroll
        for (int c = 0; c < NLD; ++c) g[s][c] = make_uint4(0u, 0u, 0u, 0u);
        if (src >= 0) {
            const u16* p = X + (size_t)src * CIN + gc * (CIN / 4);
            #pragma unroll
            for (int c = 0; c < NLD; ++c) g[s][c] = ((const uint4*)p)[c];
        }
    };
    auto store_s = [&](int k, int s) {
        u16* d = &sG[k % 3][gr * GSTR + gc * (CIN / 4)];
        #pragma unroll
        for (int c = 0; c < NLD; ++c) ((uint4*)d)[c] = g[s][c];
    };

    f32x4 acc[4] = {};
    issue(0, 0);
    issue(1, 1);
    #pragma unroll
    for (int k = 0; k < KOFF; ++k) {
        store_s(k, k & 1);                 // waits this set's loads; frees the set
        __syncthreads();                   // slot k%3 visible to all waves
        if (k + 2 < KOFF) issue(k + 2, k & 1);
        const u16* sgb = &sG[k % 3][0];
        #pragma unroll
        for (int mt = 0; mt < 4; ++mt)
            #pragma unroll
            for (int ch = 0; ch < NLD; ++ch) {
                bf16x8 afr = *(const bf16x8*)(sgb + (mt * 16 + rl) * GSTR + ch * 32 + q * 8);
                acc[mt] = __builtin_amdgcn_mfma_f32_16x16x32_bf16(afr, wreg[k][ch], acc[mt], 0, 0, 0);
            }
    }

    // ---- folded-BN bias via mask MFMA: acc += M(mask 0/1) x BW
    if constexpr (BIAS) {
        bf16x8 bw = *(const bf16x8*)(BWt + ((size_t)br * 64 + colbase + rl) * 32 + q * 8);
        #pragma unroll
        for (int mt = 0; mt < 4; ++mt) {
            bf16x8 mf = *(const bf16x8*)(sM + (mt * 16 + rl) * 32 + q * 8);
            acc[mt] = __builtin_amdgcn_mfma_f32_16x16x32_bf16(mf, bw, acc[mt], 0, 0, 0);
        }
    }

    // ---- epilogue: LeakyReLU + store + BN stats (sharded atomics)
    float ps = 0.f, pss = 0.f;
    #pragma unroll
    for (int mt = 0; mt < 4; ++mt) {
        #pragma unroll
        for (int i = 0; i < 4; ++i) {
            float v = lrelu(acc[mt][i]);
            const size_t o = (size_t)(n0 + mt * 16 + q * 4 + i) * 64 + colbase + rl;
            if (outH) outH[o] = f2bf(v);
            else      outF[o] = v;
            ps += v; pss += v * v;
        }
    }
    ps  += __shfl_xor(ps, 16);  ps  += __shfl_xor(ps, 32);
    pss += __shfl_xor(pss, 16); pss += __shfl_xor(pss, 32);
    __syncthreads();                       // all MFMA LDS reads done; reuse sG
    float* red = (float*)&sG[0][0];
    if (l < 16) { red[colbase + rl] = ps; red[64 + colbase + rl] = pss; }
    __syncthreads();
    if (tid < 128) {
        const int shard = blockIdx.x & (NSHARD - 1);
        atomicAdd(st + shard * 512 + (tid >> 6) * 64 + (tid & 63), red[tid]);
    }
}

// b<144: WtA[br][k][d][c]=bf16(W[k][c][d]);  b in [144,208): zero sharded stats;
// b>=208: feats f32 -> bf16 (into feats16), grid-stride.
__global__ void prep0(const float* __restrict__ W1, const float* __restrict__ W2,
                      const float* __restrict__ feats,
                      u16* __restrict__ WtA, float* __restrict__ stats,
                      u16* __restrict__ feats16)
{
    const int b = blockIdx.x;
    const int t = threadIdx.x;
    if (b < 144) {
        const int i = b * 256 + t;                 // 2*9*64*32 = 36864 exactly
        const int brw = i / (KOFF * 64 * 32);
        const int r  = i % (KOFF * 64 * 32);
        const int k  = r / (64 * 32);
        const int r2 = r % (64 * 32);
        const int d  = r2 / 32, c = r2 % 32;
        const float* W = brw ? W2 : W1;
        WtA[i] = f2bf(W[((size_t)k * 32 + c) * 64 + d]);
        return;
    }
    if (b < 208) {                                 // 64*256 = 16384 = NSHARD*512
        stats[(b - 144) * 256 + t] = 0.f;
        return;
    }
    const int stride = (gridDim.x - 208) * 256;
    for (int i = (b - 208) * 256 + t; i < NVOX * 32 / 8; i += stride) {
        const float4 f0 = ((const float4*)feats)[i * 2];
        const float4 f1 = ((const float4*)feats)[i * 2 + 1];
        ((uint4*)feats16)[i] = make_uint4(pkbf(f0.x, f0.y), pkbf(f0.z, f0.w),
                                          pkbf(f1.x, f1.y), pkbf(f1.z, f1.w));
    }
}

// finalize stage-A BN (sum shards, in LDS) + fold into stage-B weights:
// WtB[br][k][d][c] = bf16(W[k][c][d]*a[c]); BWt[br][d][k(pad32)] = bf16(sum_c b'[c]*W[k][c][d])
__global__ void wprepB(const float* __restrict__ W12, const float* __restrict__ W3,
                       const float* __restrict__ stats,
                       const float* __restrict__ g0, const float* __restrict__ b0,
                       const float* __restrict__ g1, const float* __restrict__ b1,
                       u16* __restrict__ WtB, u16* __restrict__ BWt)
{
    __shared__ float sa[256];                 // [br][{a[64], b'[64]}]
    const int t = threadIdx.x;
    if (t < 128) {
        const int brw = t >> 6, d = t & 63;
        float s = 0.f, ss = 0.f;
        for (int sh = 0; sh < NSHARD; ++sh) {
            s  += stats[sh * 512 + brw * 128 + d];
            ss += stats[sh * 512 + brw * 128 + 64 + d];
        }
        const float* g = brw ? g1 : g0;
        const float* bb = brw ? b1 : b0;
        const float inv_n = 1.0f / (float)NVOX;
        float mu  = s * inv_n;
        float var = ss * inv_n - mu * mu;
        float a = g[d] * rsqrtf(var + BN_EPS);
        sa[brw * 128 + d] = a;
        sa[brw * 128 + 64 + d] = bb[d] - mu * a;
    }
    __syncthreads();
    const int i = blockIdx.x * 256 + t;
    if (i >= 2 * KOFF * 64) return;
    const int brw = i / (KOFF * 64);
    const int r  = i % (KOFF * 64);
    const int k  = r / 64, d = r % 64;
    const float* W = brw ? W3 : W12;
    const float* a = sa + brw * 128;
    const float* bb = a + 64;
    float bw = 0.f;
    u16* wrow = WtB + (((size_t)brw * KOFF + k) * 64 + d) * 64;
    #pragma unroll 8
    for (int c = 0; c < 64; ++c) {
        const float wv = W[((size_t)k * 64 + c) * 64 + d];
        wrow[c] = f2bf(wv * a[c]);
        bw += wv * bb[c];
    }
    u16* brow = BWt + ((size_t)brw * 64 + d) * 32;
    brow[k] = f2bf(bw);
    if (k == 0) {
        for (int kk = KOFF; kk < 32; ++kk) brow[kk] = 0;
    }
}

// finalize stage-B BN (sum shards) + out = aff2(ys) + aff3(yr), in place over yr (= d_out)
__global__ void combine_kernel(const u16* __restrict__ ys, float* __restrict__ yr,
                               const float* __restrict__ stats,
                               const float* __restrict__ g02, const float* __restrict__ b02,
                               const float* __restrict__ g2, const float* __restrict__ b2)
{
    __shared__ float sc[256];                 // [br][{a[64], b'[64]}]; br0=ys, br1=yr
    const int t = threadIdx.x;
    if (t < 128) {
        const int brw = t >> 6, d = t & 63;
        float s = 0.f, ss = 0.f;
        for (int sh = 0; sh < NSHARD; ++sh) {
            s  += stats[sh * 512 + 256 + brw * 128 + d];
            ss += stats[sh * 512 + 256 + brw * 128 + 64 + d];
        }
        const float* g = brw ? g2 : g02;
        const float* b = brw ? b2 : b02;
        const float inv_n = 1.0f / (float)NVOX;
        float mu  = s * inv_n;
        float var = ss * inv_n - mu * mu;
        float a = g[d] * rsqrtf(var + BN_EPS);
        sc[brw * 128 + d] = a;
        sc[brw * 128 + 64 + d] = b[d] - mu * a;
    }
    __syncthreads();
    const int total = NVOX * 64 / 4;
    for (int i = blockIdx.x * blockDim.x + t; i < total; i += gridDim.x * blockDim.x) {
        const int dq = (i & 15) * 4;
        ushort4 sh = reinterpret_cast<const ushort4*>(ys)[i];
        float4 r = reinterpret_cast<const float4*>(yr)[i];
        float4 a2 = *(const float4*)(sc + dq);
        float4 b2v = *(const float4*)(sc + 64 + dq);
        float4 a3 = *(const float4*)(sc + 128 + dq);
        float4 b3v = *(const float4*)(sc + 128 + 64 + dq);
        float4 o;
        o.x = fmaf(a2.x, bf2f(sh.x), b2v.x) + fmaf(a3.x, r.x, b3v.x);
        o.y = fmaf(a2.y, bf2f(sh.y), b2v.y) + fmaf(a3.y, r.y, b3v.y);
        o.z = fmaf(a2.z, bf2f(sh.z), b2v.z) + fmaf(a3.z, r.z, b3v.z);
        o.w = fmaf(a2.w, bf2f(sh.w), b2v.w) + fmaf(a3.w, r.w, b3v.w);
        reinterpret_cast<float4*>(yr)[i] = o;
    }
}

extern "C" void kernel_launch(void* const* d_in, const int* in_sizes, int n_in,
                              void* d_out, int out_size, void* d_ws, size_t ws_size,
                              hipStream_t stream) {
    const float* feats = (const float*)d_in[0];
    const float* W1    = (const float*)d_in[1];
    const float* W12   = (const float*)d_in[2];
    const float* W2    = (const float*)d_in[3];
    const float* W3    = (const float*)d_in[4];
    const float* g0  = (const float*)d_in[5];
    const float* b0  = (const float*)d_in[6];
    const float* g02 = (const float*)d_in[7];
    const float* b02 = (const float*)d_in[8];
    const float* g1  = (const float*)d_in[9];
    const float* b1  = (const float*)d_in[10];
    const float* g2  = (const float*)d_in[11];
    const float* b2  = (const float*)d_in[12];
    const int* nbrA  = (const int*)d_in[13];
    const int* maskA = (const int*)d_in[14];   // bool delivered as int32
    const int* nbrB  = (const int*)d_in[15];
    const int* maskB = (const int*)d_in[16];

    // ws layout: bf16 activations + bf16 weights + sharded f32 stats (~77 MB).
    // feats16 (6.4M u16) aliases the ys region: read only in stage A, ys written
    // only in stage B — no overlap in lifetime.
    const size_t buf = (size_t)NVOX * 64;
    u16* y1  = (u16*)d_ws;
    u16* y2  = y1 + buf;
    u16* ys  = y2 + buf;
    u16* feats16 = ys;                   // alias (NVOX*32 u16)
    u16* WtA = ys + buf;                 // 2*9*64*32 = 36864
    u16* WtB = WtA + 2 * KOFF * 64 * 32; // 2*9*64*64 = 73728
    u16* BWt = WtB + 2 * KOFF * 64 * 64; // 2*64*32   = 4096
    float* stats = (float*)(BWt + 2 * 64 * 32);  // NSHARD x [4 x {sum[64],sumsq[64]}]
    float* outf  = (float*)d_out;        // stage-B resA output lives in d_out

    dim3 gA(NVOX / 64, 2);

    prep0<<<2000, 256, 0, stream>>>(W1, W2, feats, WtA, stats, feats16);

    // stage A: y1 = lrelu(conv(feats,nbrA,W1)); y2 = lrelu(conv(feats,nbrB,W2))
    conv_mfma<32, false><<<gA, 256, 0, stream>>>(
        feats16, feats16, nbrA, nbrB, maskA, maskB, WtA, nullptr,
        y1, y2, nullptr, nullptr, stats, stats + 128);

    wprepB<<<5, 256, 0, stream>>>(W12, W3, stats, g0, b0, g1, b1, WtB, BWt);

    // stage B: ys = lrelu(conv(bn(y1),nbrB,W12)); outf = lrelu(conv(bn(y2),nbrA,W3))
    conv_mfma<64, true><<<gA, 256, 0, stream>>>(
        y1, y2, nbrB, nbrA, maskB, maskA, WtB, BWt,
        ys, nullptr, nullptr, outf, stats + 256, stats + 384);

    combine_kernel<<<1024, 256, 0, stream>>>(ys, outf, stats, g02, b02, g2, b2);
}